// Round 12
// baseline (162.994 us; speedup 1.0000x reference)
//
#include <hip/hip_runtime.h>
#include <hip/hip_bf16.h>
#include <math.h>

#define IN_DIM 128
#define OUT_DIM 128
#define NHEAD 4
#define HC 32
#define NEG_SLOPE 0.2f
#define LN_EPS 1e-5f
#define SM_EPS 1e-16f

#define NB_SHIFT 9
#define BDST 512            // 1 << NB_SHIFT
#define NBUCK_MAX 256
#define BIN_ITER 28
#define BIN_CHUNK (BIN_ITER * 256)
#define SRC_BITS 17         // N < 131072
#define SRC_MASK ((1u << SRC_BITS) - 1u)
#define BCAP_SHIFT 14
#define BCAP (1 << BCAP_SHIFT)

typedef __attribute__((ext_vector_type(8))) short bf16x8;
typedef __attribute__((ext_vector_type(4))) short short4v;
typedef __attribute__((ext_vector_type(4))) float f32x4;

__device__ __forceinline__ float leaky(float v) { return v > 0.f ? v : NEG_SLOPE * v; }

__device__ __forceinline__ short f2b(float f) {
    __hip_bfloat16 b = __float2bfloat16(f);
    return *reinterpret_cast<short*>(&b);
}

// byte offset into a tile of 256-byte rows, XOR row-swizzled (G4 fix)
__device__ __forceinline__ int swz(int row, int byteInRow) {
    return row * 256 + (byteInRow ^ ((row & 7) << 4));
}

// ---------------- K0: W[k][j] fp32 -> WtB[j][k] bf16 (64 blocks) ----------------
__global__ void k_prepW(const float* __restrict__ W, __hip_bfloat16* __restrict__ WtB)
{
    int t0 = blockIdx.x * 256 + threadIdx.x;
    int k = t0 >> 7, j = t0 & 127;
    WtB[j * IN_DIM + k] = __float2bfloat16(W[t0]);
}

// ---------------- K1: h = x @ W via MFMA (wide LDS-repacked stores) ----------------
__global__ void __launch_bounds__(256)
k_gemm(const float* __restrict__ x, const __hip_bfloat16* __restrict__ WtB,
       __hip_bfloat16* __restrict__ hB, int N)
{
    __shared__ __align__(16) char lds[49152];   // [0,16K): xs / out-tile ; [16K,48K): Wt
    const int t = threadIdx.x;
    const int node0 = blockIdx.x * 64;

    #pragma unroll
    for (int i = 0; i < 16; ++i) {
        int idx = (i * 256 + t) * 4;
        int col = idx >> 7, k = idx & 127;
        short4v w4 = *reinterpret_cast<const short4v*>((const short*)WtB + idx);
        *reinterpret_cast<short4v*>(lds + 16384 + swz(col, 2 * k)) = w4;
    }
    #pragma unroll
    for (int i = 0; i < 8; ++i) {
        int idx = (i * 256 + t) * 4;
        int row = idx >> 7, k = idx & 127;
        int node = node0 + row;
        float4 xv = make_float4(0.f, 0.f, 0.f, 0.f);
        if (node < N) xv = *reinterpret_cast<const float4*>(x + (size_t)node * IN_DIM + k);
        short4v xb = { f2b(xv.x), f2b(xv.y), f2b(xv.z), f2b(xv.w) };
        *reinterpret_cast<short4v*>(lds + swz(row, 2 * k)) = xb;
    }
    __syncthreads();

    const int wave = t >> 6, l = t & 63;
    const int lr = l & 15, lg = l >> 4;

    bf16x8 afrag[4];
    #pragma unroll
    for (int kk = 0; kk < 4; ++kk)
        afrag[kk] = *reinterpret_cast<bf16x8*>(lds + swz(wave * 16 + lr, kk * 64 + lg * 16));

    f32x4 acc[8];
    #pragma unroll
    for (int cg = 0; cg < 8; ++cg) acc[cg] = (f32x4){0.f, 0.f, 0.f, 0.f};

    #pragma unroll
    for (int cg = 0; cg < 8; ++cg) {
        #pragma unroll
        for (int kk = 0; kk < 4; ++kk) {
            bf16x8 b = *reinterpret_cast<bf16x8*>(lds + 16384 + swz(cg * 16 + lr, kk * 64 + lg * 16));
            acc[cg] = __builtin_amdgcn_mfma_f32_16x16x32_bf16(afrag[kk], b, acc[cg], 0, 0, 0);
        }
    }

    // repack D-fragments into bf16 out-tile in LDS (xs region is dead now)
    __syncthreads();
    #pragma unroll
    for (int q = 0; q < 4; ++q) {
        int row = wave * 16 + lg * 4 + q;
        #pragma unroll
        for (int cg = 0; cg < 8; ++cg)
            *reinterpret_cast<short*>(lds + swz(row, (cg * 16 + lr) * 2)) = f2b(acc[cg][q]);
    }
    __syncthreads();

    // wide coalesced store: thread t -> row t>>2, 4x 16B chunks
    {
        int row = t >> 2;
        int node = node0 + row;
        if (node < N) {
            char* dst = (char*)(hB + (size_t)node * OUT_DIM);
            #pragma unroll
            for (int c = 0; c < 4; ++c) {
                int bir = (t & 3) * 64 + c * 16;
                bf16x8 vv = *reinterpret_cast<bf16x8*>(lds + swz(row, bir));
                *reinterpret_cast<bf16x8*>(dst + bir) = vv;
            }
        }
    }
}

// ---------------- K2: fused { edge binning | alpha from hB } ----------------
__global__ void __launch_bounds__(256)
k_bin_alpha(const int* __restrict__ ei, int* __restrict__ bcur, unsigned* __restrict__ binned,
            const __hip_bfloat16* __restrict__ hB,
            const float* __restrict__ a_src, const float* __restrict__ a_dst,
            float* __restrict__ asrc_out, float* __restrict__ adst_out,
            int E, int N, int nblk_bin, int nblk_alpha)
{
    __shared__ int cnt[NBUCK_MAX];
    __shared__ int gb[NBUCK_MAX];
    int t = threadIdx.x;

    if ((int)blockIdx.x < nblk_bin) {
        // ============== bin branch (fixed-capacity segments) ==============
        int tot = E + N;
        int base = (int)blockIdx.x * BIN_CHUNK;

        cnt[t] = 0;
        __syncthreads();

        int rk[BIN_ITER], bk[BIN_ITER], dlo[BIN_ITER];
        #pragma unroll
        for (int k = 0; k < BIN_ITER; ++k) {
            int e = base + k * 256 + t;
            bk[k] = -1; rk[k] = 0; dlo[k] = 0;
            if (e < tot) {
                int d = (e < E) ? ei[E + e] : (e - E);
                bk[k] = d >> NB_SHIFT;
                dlo[k] = d & (BDST - 1);
                rk[k] = atomicAdd(&cnt[bk[k]], 1);
            }
        }
        __syncthreads();
        gb[t] = cnt[t] ? ((t << BCAP_SHIFT) + atomicAdd(&bcur[t], cnt[t])) : 0;
        __syncthreads();
        #pragma unroll
        for (int k = 0; k < BIN_ITER; ++k) {
            int e = base + k * 256 + t;
            if (e < tot) {
                int s = (e < E) ? ei[e] : (e - E);
                binned[gb[bk[k]] + rk[k]] = (unsigned)s | ((unsigned)dlo[k] << SRC_BITS);
            }
        }
    } else {
        // ============== alpha branch: asrc/adst from bf16 h ==============
        int l = t & 63, wave = t >> 6;
        int li = l & 15, sub = l >> 4;
        int head = li >> 2;
        float as[8], ad[8];
        #pragma unroll
        for (int j = 0; j < 8; ++j) { as[j] = a_src[li * 8 + j]; ad[j] = a_dst[li * 8 + j]; }

        int blk = (int)blockIdx.x - nblk_bin;
        for (int nb = blk * 16; nb < N; nb += nblk_alpha * 16) {
            int node = nb + wave * 4 + sub;
            float s = 0.f, d = 0.f;
            if (node < N) {
                bf16x8 hb = *reinterpret_cast<const bf16x8*>(
                    (const short*)hB + (size_t)node * OUT_DIM + li * 8);
                #pragma unroll
                for (int j = 0; j < 8; ++j) {
                    float hf = __uint_as_float(((unsigned)(unsigned short)hb[j]) << 16);
                    s = fmaf(hf, as[j], s);
                    d = fmaf(hf, ad[j], d);
                }
            }
            s += __shfl_xor(s, 1, 64); s += __shfl_xor(s, 2, 64);
            d += __shfl_xor(d, 1, 64); d += __shfl_xor(d, 2, 64);
            if ((li & 3) == 0 && node < N) {
                asrc_out[node * NHEAD + head] = s;
                adst_out[node * NHEAD + head] = d;
            }
        }
    }
}

// ---------------- K3: per-bucket local CSR ----------------
__global__ void k_bucket_csr(const unsigned* __restrict__ binned, const int* __restrict__ bcur,
                             int* __restrict__ rowbeg, int* __restrict__ rowend,
                             int* __restrict__ csr_src, int N)
{
    __shared__ int cnt[BDST];
    __shared__ int s2[256];
    int b = blockIdx.x;
    int t = threadIdx.x;
    int d0 = b << NB_SHIFT;
    int base = b << BCAP_SHIFT;
    int ne = bcur[b];

    cnt[t] = 0; cnt[t + 256] = 0;
    __syncthreads();
    for (int i = t; i < ne; i += 256) {
        unsigned p = binned[base + i];
        atomicAdd(&cnt[p >> SRC_BITS], 1);
    }
    __syncthreads();
    int c0 = cnt[2 * t], c1 = cnt[2 * t + 1];
    s2[t] = c0 + c1;
    __syncthreads();
    #pragma unroll
    for (int off = 1; off < 256; off <<= 1) {
        int tmp = (t >= off) ? s2[t - off] : 0;
        __syncthreads();
        s2[t] += tmp;
        __syncthreads();
    }
    int e0 = (t ? s2[t - 1] : 0);
    cnt[2 * t] = e0;
    cnt[2 * t + 1] = e0 + c0;
    if (d0 + 2 * t < N) {
        rowbeg[d0 + 2 * t] = base + e0;
        rowend[d0 + 2 * t] = base + e0 + c0;
    }
    if (d0 + 2 * t + 1 < N) {
        rowbeg[d0 + 2 * t + 1] = base + e0 + c0;
        rowend[d0 + 2 * t + 1] = base + e0 + c0 + c1;
    }
    __syncthreads();
    for (int i = t; i < ne; i += 256) {
        unsigned p = binned[base + i];
        int r = atomicAdd(&cnt[p >> SRC_BITS], 1);
        csr_src[base + r] = (int)(p & SRC_MASK);
    }
}

// ---------------- K4: gather + softmax + aggregate + bias + LN + ReLU ----------------
__global__ void k_gather(const int* __restrict__ csr_src,
                         const int* __restrict__ rowbeg, const int* __restrict__ rowend,
                         const __hip_bfloat16* __restrict__ hB,
                         const float* __restrict__ asrc, const float* __restrict__ adst,
                         const float* __restrict__ bias, const float* __restrict__ gamma,
                         const float* __restrict__ beta, float* __restrict__ out, int N)
{
    int wave = threadIdx.x >> 6;
    int l = threadIdx.x & 63;
    int d = blockIdx.x * 4 + wave;
    if (d >= N) return;
    int head = l >> 4;
    const char* hp = (const char*)hB;
    unsigned voff = (unsigned)(l << 2);
    float ad = adst[d * NHEAD + head];
    int beg = __builtin_amdgcn_readfirstlane(rowbeg[d]);
    int end = __builtin_amdgcn_readfirstlane(rowend[d]);

    float ax0 = 0.f, ay0 = 0.f, dn0 = 0.f;
    float ax1 = 0.f, ay1 = 0.f, dn1 = 0.f;

    int idx = beg + (l & 15);
    int cl = idx < end ? idx : end - 1;
    int smine = csr_src[cl];
    float v = (idx < end) ? asrc[(unsigned)smine * NHEAD + head] : -1e30f;

    for (int c = beg; c < end; c += 16) {
        float ee = __expf(leaky(v + ad));        // padding -> exp(-2e29) = 0
        int scur = smine;
        int c2 = c + 16;
        if (c2 < end) {
            int idx2 = c2 + (l & 15);
            int cl2 = idx2 < end ? idx2 : end - 1;
            smine = csr_src[cl2];
            v = (idx2 < end) ? asrc[(unsigned)smine * NHEAD + head] : -1e30f;
        }

#define GLOAD(E_)                                                                     \
        unsigned se##E_ = (unsigned)__builtin_amdgcn_readlane(scur, (E_));            \
        unsigned hv##E_ = *(const unsigned*)(hp + ((size_t)se##E_ << 8) + voff);
#define GCONS(E_, AX_, AY_, DN_) {                                                    \
        float eb = __int_as_float(__builtin_amdgcn_ds_swizzle(                        \
            __float_as_int(ee), 0x10 | ((E_) << 5)));                                 \
        AX_ = fmaf(eb, __uint_as_float(hv##E_ << 16), AX_);                           \
        AY_ = fmaf(eb, __uint_as_float(hv##E_ & 0xffff0000u), AY_);  DN_ += eb;       \
    }
        { GLOAD(0) GLOAD(1) GLOAD(2) GLOAD(3) GLOAD(4) GLOAD(5) GLOAD(6) GLOAD(7)
          GCONS(0, ax0, ay0, dn0) GCONS(1, ax1, ay1, dn1)
          GCONS(2, ax0, ay0, dn0) GCONS(3, ax1, ay1, dn1)
          GCONS(4, ax0, ay0, dn0) GCONS(5, ax1, ay1, dn1)
          GCONS(6, ax0, ay0, dn0) GCONS(7, ax1, ay1, dn1) }
        { GLOAD(8) GLOAD(9) GLOAD(10) GLOAD(11) GLOAD(12) GLOAD(13) GLOAD(14) GLOAD(15)
          GCONS(8, ax0, ay0, dn0)  GCONS(9, ax1, ay1, dn1)
          GCONS(10, ax0, ay0, dn0) GCONS(11, ax1, ay1, dn1)
          GCONS(12, ax0, ay0, dn0) GCONS(13, ax1, ay1, dn1)
          GCONS(14, ax0, ay0, dn0) GCONS(15, ax1, ay1, dn1) }
#undef GLOAD
#undef GCONS
    }

    float accx = ax0 + ax1, accy = ay0 + ay1, den = dn0 + dn1;
    float inv = 1.f / (den + SM_EPS);
    float vx = accx * inv + bias[2 * l];
    float vy = accy * inv + bias[2 * l + 1];

    float s1 = vx + vy;
    float s2 = vx * vx + vy * vy;
    #pragma unroll
    for (int m = 32; m >= 1; m >>= 1) {
        s1 += __shfl_xor(s1, m, 64);
        s2 += __shfl_xor(s2, m, 64);
    }
    float mean = s1 * (1.f / OUT_DIM);
    float var = s2 * (1.f / OUT_DIM) - mean * mean;
    float r = rsqrtf(var + LN_EPS);
    float ox = (vx - mean) * r * gamma[2 * l] + beta[2 * l];
    float oy = (vy - mean) * r * gamma[2 * l + 1] + beta[2 * l + 1];
    ox = ox > 0.f ? ox : 0.f;
    oy = oy > 0.f ? oy : 0.f;
    *reinterpret_cast<float2*>(&out[(size_t)d * OUT_DIM + 2 * l]) = make_float2(ox, oy);
}

extern "C" void kernel_launch(void* const* d_in, const int* in_sizes, int n_in,
                              void* d_out, int out_size, void* d_ws, size_t ws_size,
                              hipStream_t stream) {
    const float* x      = (const float*)d_in[0];
    const int*   ei     = (const int*)d_in[1];
    const float* W      = (const float*)d_in[2];
    const float* a_src  = (const float*)d_in[3];
    const float* a_dst  = (const float*)d_in[4];
    const float* bias   = (const float*)d_in[5];
    const float* gamma  = (const float*)d_in[6];
    const float* beta   = (const float*)d_in[7];
    float* out = (float*)d_out;

    const int N = in_sizes[0] / IN_DIM;
    const int E = in_sizes[1] / 2;
    const int TOT = E + N;
    const int nbuck = (N + BDST - 1) >> NB_SHIFT;
    const int nblk_gemm = (N + 63) / 64;
    const int nblk_bin = (TOT + BIN_CHUNK - 1) / BIN_CHUNK;
    const int nblk_alpha = 256;

    // workspace layout
    char* p = (char*)d_ws;
    __hip_bfloat16* hB = (__hip_bfloat16*)p;  p += (size_t)N * OUT_DIM * sizeof(__hip_bfloat16);
    __hip_bfloat16* WtB = (__hip_bfloat16*)p; p += (size_t)IN_DIM * OUT_DIM * sizeof(__hip_bfloat16);
    float* asrc   = (float*)p;                p += (size_t)N * NHEAD * sizeof(float);
    float* adst   = (float*)p;                p += (size_t)N * NHEAD * sizeof(float);
    int* bcur     = (int*)p;                  p += NBUCK_MAX * sizeof(int);
    int* rowbeg   = (int*)p;                  p += (size_t)N * sizeof(int);
    int* rowend   = (int*)p;                  p += (size_t)N * sizeof(int);
    unsigned* binned = (unsigned*)p;          p += (size_t)nbuck * BCAP * sizeof(unsigned);
    int* csr_src  = (int*)p;                  p += (size_t)nbuck * BCAP * sizeof(int);

    (void)hipMemsetAsync(bcur, 0, NBUCK_MAX * sizeof(int), stream);

    k_prepW<<<64, 256, 0, stream>>>(W, WtB);
    k_gemm<<<nblk_gemm, 256, 0, stream>>>(x, WtB, hB, N);
    k_bin_alpha<<<nblk_bin + nblk_alpha, 256, 0, stream>>>(ei, bcur, binned, hB, a_src, a_dst,
                                                           asrc, adst, E, N, nblk_bin, nblk_alpha);
    k_bucket_csr<<<nbuck, 256, 0, stream>>>(binned, bcur, rowbeg, rowend, csr_src, N);
    k_gather<<<(N + 3) / 4, 256, 0, stream>>>(csr_src, rowbeg, rowend, hB, asrc, adst,
                                              bias, gamma, beta, out, N);
}

// Round 13
// 159.343 us; speedup vs baseline: 1.0229x; 1.0229x over previous
//
#include <hip/hip_runtime.h>
#include <hip/hip_bf16.h>
#include <math.h>

#define IN_DIM 128
#define OUT_DIM 128
#define NHEAD 4
#define HC 32
#define NEG_SLOPE 0.2f
#define LN_EPS 1e-5f
#define SM_EPS 1e-16f

#define NB_SHIFT 9
#define BDST 512            // 1 << NB_SHIFT
#define NBUCK_MAX 256
#define BIN_ITER 28
#define BIN_CHUNK (BIN_ITER * 256)
#define SRC_BITS 17         // N < 131072
#define SRC_MASK ((1u << SRC_BITS) - 1u)
#define BCAP_SHIFT 14
#define BCAP (1 << BCAP_SHIFT)

typedef __attribute__((ext_vector_type(8))) short bf16x8;
typedef __attribute__((ext_vector_type(4))) short short4v;
typedef __attribute__((ext_vector_type(4))) float f32x4;

__device__ __forceinline__ float leaky(float v) { return v > 0.f ? v : NEG_SLOPE * v; }

__device__ __forceinline__ short f2b(float f) {
    __hip_bfloat16 b = __float2bfloat16(f);
    return *reinterpret_cast<short*>(&b);
}
__device__ __forceinline__ float b2f(short s) {
    return __uint_as_float(((unsigned)(unsigned short)s) << 16);
}

// byte offset into a tile of 256-byte rows, XOR row-swizzled (G4 fix)
__device__ __forceinline__ int swz(int row, int byteInRow) {
    return row * 256 + (byteInRow ^ ((row & 7) << 4));
}

// ---------------- K0: W[k][j] fp32 -> WtB[j][k] bf16 (64 blocks) + zero bcur ----------------
__global__ void k_prepW(const float* __restrict__ W, __hip_bfloat16* __restrict__ WtB,
                        int* __restrict__ bcur)
{
    int t0 = blockIdx.x * 256 + threadIdx.x;
    int k = t0 >> 7, j = t0 & 127;
    WtB[j * IN_DIM + k] = __float2bfloat16(W[t0]);
    if (blockIdx.x == 0) bcur[threadIdx.x] = 0;
}

// ---------------- K1: fused { MFMA GEMM + alpha | edge binning } ----------------
__global__ void __launch_bounds__(256)
k_gemm_bin(const float* __restrict__ x, const __hip_bfloat16* __restrict__ WtB,
           const float* __restrict__ a_src, const float* __restrict__ a_dst,
           __hip_bfloat16* __restrict__ hB, float* __restrict__ asrc_out,
           float* __restrict__ adst_out,
           const int* __restrict__ ei, int* __restrict__ bcur,
           unsigned* __restrict__ binned,
           int E, int N, int nblk_gemm)
{
    __shared__ __align__(16) char lds[49152];   // gemm: [0,16K) xs/out ; [16K,48K) Wt
    const int t = threadIdx.x;

    if ((int)blockIdx.x < nblk_gemm) {
        // ================= GEMM + alpha branch =================
        const int node0 = blockIdx.x * 64;

        #pragma unroll
        for (int i = 0; i < 16; ++i) {
            int idx = (i * 256 + t) * 4;
            int col = idx >> 7, k = idx & 127;
            short4v w4 = *reinterpret_cast<const short4v*>((const short*)WtB + idx);
            *reinterpret_cast<short4v*>(lds + 16384 + swz(col, 2 * k)) = w4;
        }
        #pragma unroll
        for (int i = 0; i < 8; ++i) {
            int idx = (i * 256 + t) * 4;
            int row = idx >> 7, k = idx & 127;
            int node = node0 + row;
            float4 xv = make_float4(0.f, 0.f, 0.f, 0.f);
            if (node < N) xv = *reinterpret_cast<const float4*>(x + (size_t)node * IN_DIM + k);
            short4v xb = { f2b(xv.x), f2b(xv.y), f2b(xv.z), f2b(xv.w) };
            *reinterpret_cast<short4v*>(lds + swz(row, 2 * k)) = xb;
        }
        __syncthreads();

        const int wave = t >> 6, l = t & 63;
        const int lr = l & 15, lg = l >> 4;

        bf16x8 afrag[4];
        #pragma unroll
        for (int kk = 0; kk < 4; ++kk)
            afrag[kk] = *reinterpret_cast<bf16x8*>(lds + swz(wave * 16 + lr, kk * 64 + lg * 16));

        f32x4 acc[8];
        #pragma unroll
        for (int cg = 0; cg < 8; ++cg) acc[cg] = (f32x4){0.f, 0.f, 0.f, 0.f};

        #pragma unroll
        for (int cg = 0; cg < 8; ++cg) {
            #pragma unroll
            for (int kk = 0; kk < 4; ++kk) {
                bf16x8 b = *reinterpret_cast<bf16x8*>(lds + 16384 + swz(cg * 16 + lr, kk * 64 + lg * 16));
                acc[cg] = __builtin_amdgcn_mfma_f32_16x16x32_bf16(afrag[kk], b, acc[cg], 0, 0, 0);
            }
        }

        // repack D-fragments into bf16 out-tile in LDS (xs region is dead now)
        __syncthreads();
        #pragma unroll
        for (int q = 0; q < 4; ++q) {
            int row = wave * 16 + lg * 4 + q;
            #pragma unroll
            for (int cg = 0; cg < 8; ++cg)
                *reinterpret_cast<short*>(lds + swz(row, (cg * 16 + lr) * 2)) = f2b(acc[cg][q]);
        }
        __syncthreads();

        // wide coalesced store + fused alpha: thread t -> row t>>2, head t&3
        {
            int row = t >> 2;
            int node = node0 + row;
            int head = t & 3;
            if (node < N) {
                char* dst = (char*)(hB + (size_t)node * OUT_DIM);
                float s = 0.f, dd = 0.f;
                #pragma unroll
                for (int c = 0; c < 4; ++c) {
                    int bir = head * 64 + c * 16;
                    bf16x8 vv = *reinterpret_cast<bf16x8*>(lds + swz(row, bir));
                    *reinterpret_cast<bf16x8*>(dst + bir) = vv;
                    #pragma unroll
                    for (int j = 0; j < 8; ++j) {
                        float hf = b2f(vv[j]);
                        s  = fmaf(hf, a_src[head * HC + c * 8 + j], s);
                        dd = fmaf(hf, a_dst[head * HC + c * 8 + j], dd);
                    }
                }
                asrc_out[node * NHEAD + head] = s;
                adst_out[node * NHEAD + head] = dd;
            }
        }
    } else {
        // ================= bin branch (fixed-capacity segments) =================
        int* cnt = (int*)lds;
        int* gb  = (int*)(lds + 1024);
        int tot = E + N;
        int base = ((int)blockIdx.x - nblk_gemm) * BIN_CHUNK;

        cnt[t] = 0;
        __syncthreads();

        int rk[BIN_ITER], bk[BIN_ITER], dlo[BIN_ITER];
        #pragma unroll
        for (int k = 0; k < BIN_ITER; ++k) {
            int e = base + k * 256 + t;
            bk[k] = -1; rk[k] = 0; dlo[k] = 0;
            if (e < tot) {
                int d = (e < E) ? ei[E + e] : (e - E);
                bk[k] = d >> NB_SHIFT;
                dlo[k] = d & (BDST - 1);
                rk[k] = atomicAdd(&cnt[bk[k]], 1);
            }
        }
        __syncthreads();
        gb[t] = cnt[t] ? ((t << BCAP_SHIFT) + atomicAdd(&bcur[t], cnt[t])) : 0;
        __syncthreads();
        #pragma unroll
        for (int k = 0; k < BIN_ITER; ++k) {
            int e = base + k * 256 + t;
            if (e < tot) {
                int s = (e < E) ? ei[e] : (e - E);
                binned[gb[bk[k]] + rk[k]] = (unsigned)s | ((unsigned)dlo[k] << SRC_BITS);
            }
        }
    }
}

// ---------------- K3: per-bucket local CSR ----------------
__global__ void k_bucket_csr(const unsigned* __restrict__ binned, const int* __restrict__ bcur,
                             int* __restrict__ rowbeg, int* __restrict__ rowend,
                             int* __restrict__ csr_src, int N)
{
    __shared__ int cnt[BDST];
    __shared__ int s2[256];
    int b = blockIdx.x;
    int t = threadIdx.x;
    int d0 = b << NB_SHIFT;
    int base = b << BCAP_SHIFT;
    int ne = bcur[b];

    cnt[t] = 0; cnt[t + 256] = 0;
    __syncthreads();
    for (int i = t; i < ne; i += 256) {
        unsigned p = binned[base + i];
        atomicAdd(&cnt[p >> SRC_BITS], 1);
    }
    __syncthreads();
    int c0 = cnt[2 * t], c1 = cnt[2 * t + 1];
    s2[t] = c0 + c1;
    __syncthreads();
    #pragma unroll
    for (int off = 1; off < 256; off <<= 1) {
        int tmp = (t >= off) ? s2[t - off] : 0;
        __syncthreads();
        s2[t] += tmp;
        __syncthreads();
    }
    int e0 = (t ? s2[t - 1] : 0);
    cnt[2 * t] = e0;
    cnt[2 * t + 1] = e0 + c0;
    if (d0 + 2 * t < N) {
        rowbeg[d0 + 2 * t] = base + e0;
        rowend[d0 + 2 * t] = base + e0 + c0;
    }
    if (d0 + 2 * t + 1 < N) {
        rowbeg[d0 + 2 * t + 1] = base + e0 + c0;
        rowend[d0 + 2 * t + 1] = base + e0 + c0 + c1;
    }
    __syncthreads();
    for (int i = t; i < ne; i += 256) {
        unsigned p = binned[base + i];
        int r = atomicAdd(&cnt[p >> SRC_BITS], 1);
        csr_src[base + r] = (int)(p & SRC_MASK);
    }
}

// ---------------- K4: gather + softmax + aggregate + bias + LN + ReLU ----------------
__global__ void k_gather(const int* __restrict__ csr_src,
                         const int* __restrict__ rowbeg, const int* __restrict__ rowend,
                         const __hip_bfloat16* __restrict__ hB,
                         const float* __restrict__ asrc, const float* __restrict__ adst,
                         const float* __restrict__ bias, const float* __restrict__ gamma,
                         const float* __restrict__ beta, float* __restrict__ out, int N)
{
    int wave = threadIdx.x >> 6;
    int l = threadIdx.x & 63;
    int d = blockIdx.x * 4 + wave;
    if (d >= N) return;
    int head = l >> 4;
    const char* hp = (const char*)hB;
    unsigned voff = (unsigned)(l << 2);
    float ad = adst[d * NHEAD + head];
    int beg = __builtin_amdgcn_readfirstlane(rowbeg[d]);
    int end = __builtin_amdgcn_readfirstlane(rowend[d]);

    float ax0 = 0.f, ay0 = 0.f, dn0 = 0.f;
    float ax1 = 0.f, ay1 = 0.f, dn1 = 0.f;

    int idx = beg + (l & 15);
    int cl = idx < end ? idx : end - 1;
    int smine = csr_src[cl];
    float v = (idx < end) ? asrc[(unsigned)smine * NHEAD + head] : -1e30f;

    for (int c = beg; c < end; c += 16) {
        float ee = __expf(leaky(v + ad));        // padding -> exp(-2e29) = 0
        int scur = smine;
        int c2 = c + 16;
        if (c2 < end) {
            int idx2 = c2 + (l & 15);
            int cl2 = idx2 < end ? idx2 : end - 1;
            smine = csr_src[cl2];
            v = (idx2 < end) ? asrc[(unsigned)smine * NHEAD + head] : -1e30f;
        }

#define GLOAD(E_)                                                                     \
        unsigned se##E_ = (unsigned)__builtin_amdgcn_readlane(scur, (E_));            \
        unsigned hv##E_ = *(const unsigned*)(hp + ((size_t)se##E_ << 8) + voff);
#define GCONS(E_, AX_, AY_, DN_) {                                                    \
        float eb = __int_as_float(__builtin_amdgcn_ds_swizzle(                        \
            __float_as_int(ee), 0x10 | ((E_) << 5)));                                 \
        AX_ = fmaf(eb, __uint_as_float(hv##E_ << 16), AX_);                           \
        AY_ = fmaf(eb, __uint_as_float(hv##E_ & 0xffff0000u), AY_);  DN_ += eb;       \
    }
        { GLOAD(0) GLOAD(1) GLOAD(2) GLOAD(3) GLOAD(4) GLOAD(5) GLOAD(6) GLOAD(7)
          GCONS(0, ax0, ay0, dn0) GCONS(1, ax1, ay1, dn1)
          GCONS(2, ax0, ay0, dn0) GCONS(3, ax1, ay1, dn1)
          GCONS(4, ax0, ay0, dn0) GCONS(5, ax1, ay1, dn1)
          GCONS(6, ax0, ay0, dn0) GCONS(7, ax1, ay1, dn1) }
        { GLOAD(8) GLOAD(9) GLOAD(10) GLOAD(11) GLOAD(12) GLOAD(13) GLOAD(14) GLOAD(15)
          GCONS(8, ax0, ay0, dn0)  GCONS(9, ax1, ay1, dn1)
          GCONS(10, ax0, ay0, dn0) GCONS(11, ax1, ay1, dn1)
          GCONS(12, ax0, ay0, dn0) GCONS(13, ax1, ay1, dn1)
          GCONS(14, ax0, ay0, dn0) GCONS(15, ax1, ay1, dn1) }
#undef GLOAD
#undef GCONS
    }

    float accx = ax0 + ax1, accy = ay0 + ay1, den = dn0 + dn1;
    float inv = 1.f / (den + SM_EPS);
    float vx = accx * inv + bias[2 * l];
    float vy = accy * inv + bias[2 * l + 1];

    float s1 = vx + vy;
    float s2 = vx * vx + vy * vy;
    #pragma unroll
    for (int m = 32; m >= 1; m >>= 1) {
        s1 += __shfl_xor(s1, m, 64);
        s2 += __shfl_xor(s2, m, 64);
    }
    float mean = s1 * (1.f / OUT_DIM);
    float var = s2 * (1.f / OUT_DIM) - mean * mean;
    float r = rsqrtf(var + LN_EPS);
    float ox = (vx - mean) * r * gamma[2 * l] + beta[2 * l];
    float oy = (vy - mean) * r * gamma[2 * l + 1] + beta[2 * l + 1];
    ox = ox > 0.f ? ox : 0.f;
    oy = oy > 0.f ? oy : 0.f;
    *reinterpret_cast<float2*>(&out[(size_t)d * OUT_DIM + 2 * l]) = make_float2(ox, oy);
}

extern "C" void kernel_launch(void* const* d_in, const int* in_sizes, int n_in,
                              void* d_out, int out_size, void* d_ws, size_t ws_size,
                              hipStream_t stream) {
    const float* x      = (const float*)d_in[0];
    const int*   ei     = (const int*)d_in[1];
    const float* W      = (const float*)d_in[2];
    const float* a_src  = (const float*)d_in[3];
    const float* a_dst  = (const float*)d_in[4];
    const float* bias   = (const float*)d_in[5];
    const float* gamma  = (const float*)d_in[6];
    const float* beta   = (const float*)d_in[7];
    float* out = (float*)d_out;

    const int N = in_sizes[0] / IN_DIM;
    const int E = in_sizes[1] / 2;
    const int TOT = E + N;
    const int nbuck = (N + BDST - 1) >> NB_SHIFT;
    const int nblk_gemm = (N + 63) / 64;
    const int nblk_bin = (TOT + BIN_CHUNK - 1) / BIN_CHUNK;

    // workspace layout
    char* p = (char*)d_ws;
    __hip_bfloat16* hB = (__hip_bfloat16*)p;  p += (size_t)N * OUT_DIM * sizeof(__hip_bfloat16);
    __hip_bfloat16* WtB = (__hip_bfloat16*)p; p += (size_t)IN_DIM * OUT_DIM * sizeof(__hip_bfloat16);
    float* asrc   = (float*)p;                p += (size_t)N * NHEAD * sizeof(float);
    float* adst   = (float*)p;                p += (size_t)N * NHEAD * sizeof(float);
    int* bcur     = (int*)p;                  p += NBUCK_MAX * sizeof(int);
    int* rowbeg   = (int*)p;                  p += (size_t)N * sizeof(int);
    int* rowend   = (int*)p;                  p += (size_t)N * sizeof(int);
    unsigned* binned = (unsigned*)p;          p += (size_t)nbuck * BCAP * sizeof(unsigned);
    int* csr_src  = (int*)p;                  p += (size_t)nbuck * BCAP * sizeof(int);

    k_prepW<<<64, 256, 0, stream>>>(W, WtB, bcur);
    k_gemm_bin<<<nblk_gemm + nblk_bin, 256, 0, stream>>>(x, WtB, a_src, a_dst, hB, asrc, adst,
                                                         ei, bcur, binned, E, N, nblk_gemm);
    k_bucket_csr<<<nbuck, 256, 0, stream>>>(binned, bcur, rowbeg, rowend, csr_src, N);
    k_gather<<<(N + 3) / 4, 256, 0, stream>>>(csr_src, rowbeg, rowend, hB, asrc, adst,
                                              bias, gamma, beta, out, N);
}

// Round 14
// 150.773 us; speedup vs baseline: 1.0811x; 1.0568x over previous
//
#include <hip/hip_runtime.h>
#include <hip/hip_bf16.h>
#include <math.h>

#define IN_DIM 128
#define OUT_DIM 128
#define NHEAD 4
#define HC 32
#define NEG_SLOPE 0.2f
#define LN_EPS 1e-5f
#define SM_EPS 1e-16f

#define NB_SHIFT 9
#define BDST 512            // 1 << NB_SHIFT
#define NBUCK_MAX 256
#define BIN_ITER 28
#define BIN_CHUNK (BIN_ITER * 256)
#define SRC_BITS 17         // N < 131072
#define SRC_MASK ((1u << SRC_BITS) - 1u)
#define BCAP_SHIFT 14
#define BCAP (1 << BCAP_SHIFT)

typedef __attribute__((ext_vector_type(8))) short bf16x8;
typedef __attribute__((ext_vector_type(4))) short short4v;
typedef __attribute__((ext_vector_type(4))) float f32x4;

__device__ __forceinline__ float leaky(float v) { return v > 0.f ? v : NEG_SLOPE * v; }

__device__ __forceinline__ short f2b(float f) {
    __hip_bfloat16 b = __float2bfloat16(f);
    return *reinterpret_cast<short*>(&b);
}
__device__ __forceinline__ float b2f(short s) {
    return __uint_as_float(((unsigned)(unsigned short)s) << 16);
}

// byte offset into a tile of 256-byte rows, XOR row-swizzled (G4 fix)
__device__ __forceinline__ int swz(int row, int byteInRow) {
    return row * 256 + (byteInRow ^ ((row & 7) << 4));
}

// ---------------- K0: W[k][j] fp32 -> WtB[j][k] bf16 (64 blocks) + zero bcur ----------------
__global__ void k_prepW(const float* __restrict__ W, __hip_bfloat16* __restrict__ WtB,
                        int* __restrict__ bcur)
{
    int t0 = blockIdx.x * 256 + threadIdx.x;
    int k = t0 >> 7, j = t0 & 127;
    WtB[j * IN_DIM + k] = __float2bfloat16(W[t0]);
    if (blockIdx.x == 0) bcur[threadIdx.x] = 0;
}

// ---------------- K1: fused { edge binning (first) | MFMA GEMM + alpha } ----------------
// bin blocks at LOW blockIdx so they dispatch alongside the first gemm wave -> true overlap.
__global__ void __launch_bounds__(256)
k_gemm_bin(const float* __restrict__ x, const __hip_bfloat16* __restrict__ WtB,
           const float* __restrict__ a_src, const float* __restrict__ a_dst,
           __hip_bfloat16* __restrict__ hB, float* __restrict__ asrc_out,
           float* __restrict__ adst_out,
           const int* __restrict__ ei, int* __restrict__ bcur,
           unsigned* __restrict__ binned,
           int E, int N, int nblk_bin)
{
    __shared__ __align__(16) char lds[49152];   // gemm: [0,16K) xs/out ; [16K,48K) Wt
    const int t = threadIdx.x;

    if ((int)blockIdx.x < nblk_bin) {
        // ================= bin branch (fixed-capacity segments) =================
        int* cnt = (int*)lds;
        int* gb  = (int*)(lds + 1024);
        int tot = E + N;
        int base = (int)blockIdx.x * BIN_CHUNK;

        cnt[t] = 0;
        __syncthreads();

        int rk[BIN_ITER], bk[BIN_ITER], dlo[BIN_ITER];
        #pragma unroll
        for (int k = 0; k < BIN_ITER; ++k) {
            int e = base + k * 256 + t;
            bk[k] = -1; rk[k] = 0; dlo[k] = 0;
            if (e < tot) {
                int d = (e < E) ? ei[E + e] : (e - E);
                bk[k] = d >> NB_SHIFT;
                dlo[k] = d & (BDST - 1);
                rk[k] = atomicAdd(&cnt[bk[k]], 1);
            }
        }
        __syncthreads();
        gb[t] = cnt[t] ? ((t << BCAP_SHIFT) + atomicAdd(&bcur[t], cnt[t])) : 0;
        __syncthreads();
        #pragma unroll
        for (int k = 0; k < BIN_ITER; ++k) {
            int e = base + k * 256 + t;
            if (e < tot) {
                int s = (e < E) ? ei[e] : (e - E);
                binned[gb[bk[k]] + rk[k]] = (unsigned)s | ((unsigned)dlo[k] << SRC_BITS);
            }
        }
    } else {
        // ================= GEMM + alpha branch =================
        const int node0 = ((int)blockIdx.x - nblk_bin) * 64;

        #pragma unroll
        for (int i = 0; i < 16; ++i) {
            int idx = (i * 256 + t) * 4;
            int col = idx >> 7, k = idx & 127;
            short4v w4 = *reinterpret_cast<const short4v*>((const short*)WtB + idx);
            *reinterpret_cast<short4v*>(lds + 16384 + swz(col, 2 * k)) = w4;
        }
        #pragma unroll
        for (int i = 0; i < 8; ++i) {
            int idx = (i * 256 + t) * 4;
            int row = idx >> 7, k = idx & 127;
            int node = node0 + row;
            float4 xv = make_float4(0.f, 0.f, 0.f, 0.f);
            if (node < N) xv = *reinterpret_cast<const float4*>(x + (size_t)node * IN_DIM + k);
            short4v xb = { f2b(xv.x), f2b(xv.y), f2b(xv.z), f2b(xv.w) };
            *reinterpret_cast<short4v*>(lds + swz(row, 2 * k)) = xb;
        }
        __syncthreads();

        const int wave = t >> 6, l = t & 63;
        const int lr = l & 15, lg = l >> 4;

        bf16x8 afrag[4];
        #pragma unroll
        for (int kk = 0; kk < 4; ++kk)
            afrag[kk] = *reinterpret_cast<bf16x8*>(lds + swz(wave * 16 + lr, kk * 64 + lg * 16));

        f32x4 acc[8];
        #pragma unroll
        for (int cg = 0; cg < 8; ++cg) acc[cg] = (f32x4){0.f, 0.f, 0.f, 0.f};

        #pragma unroll
        for (int cg = 0; cg < 8; ++cg) {
            #pragma unroll
            for (int kk = 0; kk < 4; ++kk) {
                bf16x8 b = *reinterpret_cast<bf16x8*>(lds + 16384 + swz(cg * 16 + lr, kk * 64 + lg * 16));
                acc[cg] = __builtin_amdgcn_mfma_f32_16x16x32_bf16(afrag[kk], b, acc[cg], 0, 0, 0);
            }
        }

        // repack D-fragments into bf16 out-tile in LDS (xs region is dead now)
        __syncthreads();
        #pragma unroll
        for (int q = 0; q < 4; ++q) {
            int row = wave * 16 + lg * 4 + q;
            #pragma unroll
            for (int cg = 0; cg < 8; ++cg)
                *reinterpret_cast<short*>(lds + swz(row, (cg * 16 + lr) * 2)) = f2b(acc[cg][q]);
        }
        __syncthreads();

        // wide coalesced store + fused alpha: thread t -> row t>>2, head t&3
        {
            int row = t >> 2;
            int node = node0 + row;
            int head = t & 3;
            if (node < N) {
                char* dst = (char*)(hB + (size_t)node * OUT_DIM);
                const float4* asv = (const float4*)(a_src + head * HC);
                const float4* adv = (const float4*)(a_dst + head * HC);
                float s = 0.f, dd = 0.f;
                #pragma unroll
                for (int c = 0; c < 4; ++c) {
                    int bir = head * 64 + c * 16;
                    bf16x8 vv = *reinterpret_cast<bf16x8*>(lds + swz(row, bir));
                    *reinterpret_cast<bf16x8*>(dst + bir) = vv;
                    float4 a0 = asv[c * 2], a1 = asv[c * 2 + 1];
                    float4 d0 = adv[c * 2], d1 = adv[c * 2 + 1];
                    s  = fmaf(b2f(vv[0]), a0.x, s);  dd = fmaf(b2f(vv[0]), d0.x, dd);
                    s  = fmaf(b2f(vv[1]), a0.y, s);  dd = fmaf(b2f(vv[1]), d0.y, dd);
                    s  = fmaf(b2f(vv[2]), a0.z, s);  dd = fmaf(b2f(vv[2]), d0.z, dd);
                    s  = fmaf(b2f(vv[3]), a0.w, s);  dd = fmaf(b2f(vv[3]), d0.w, dd);
                    s  = fmaf(b2f(vv[4]), a1.x, s);  dd = fmaf(b2f(vv[4]), d1.x, dd);
                    s  = fmaf(b2f(vv[5]), a1.y, s);  dd = fmaf(b2f(vv[5]), d1.y, dd);
                    s  = fmaf(b2f(vv[6]), a1.z, s);  dd = fmaf(b2f(vv[6]), d1.z, dd);
                    s  = fmaf(b2f(vv[7]), a1.w, s);  dd = fmaf(b2f(vv[7]), d1.w, dd);
                }
                asrc_out[node * NHEAD + head] = s;
                adst_out[node * NHEAD + head] = dd;
            }
        }
    }
}

// ---------------- K3: per-bucket local CSR ----------------
__global__ void k_bucket_csr(const unsigned* __restrict__ binned, const int* __restrict__ bcur,
                             int* __restrict__ rowbeg, int* __restrict__ rowend,
                             int* __restrict__ csr_src, int N)
{
    __shared__ int cnt[BDST];
    __shared__ int s2[256];
    int b = blockIdx.x;
    int t = threadIdx.x;
    int d0 = b << NB_SHIFT;
    int base = b << BCAP_SHIFT;
    int ne = bcur[b];

    cnt[t] = 0; cnt[t + 256] = 0;
    __syncthreads();
    for (int i = t; i < ne; i += 256) {
        unsigned p = binned[base + i];
        atomicAdd(&cnt[p >> SRC_BITS], 1);
    }
    __syncthreads();
    int c0 = cnt[2 * t], c1 = cnt[2 * t + 1];
    s2[t] = c0 + c1;
    __syncthreads();
    #pragma unroll
    for (int off = 1; off < 256; off <<= 1) {
        int tmp = (t >= off) ? s2[t - off] : 0;
        __syncthreads();
        s2[t] += tmp;
        __syncthreads();
    }
    int e0 = (t ? s2[t - 1] : 0);
    cnt[2 * t] = e0;
    cnt[2 * t + 1] = e0 + c0;
    if (d0 + 2 * t < N) {
        rowbeg[d0 + 2 * t] = base + e0;
        rowend[d0 + 2 * t] = base + e0 + c0;
    }
    if (d0 + 2 * t + 1 < N) {
        rowbeg[d0 + 2 * t + 1] = base + e0 + c0;
        rowend[d0 + 2 * t + 1] = base + e0 + c0 + c1;
    }
    __syncthreads();
    for (int i = t; i < ne; i += 256) {
        unsigned p = binned[base + i];
        int r = atomicAdd(&cnt[p >> SRC_BITS], 1);
        csr_src[base + r] = (int)(p & SRC_MASK);
    }
}

// ---------------- K4: gather + softmax + aggregate + bias + LN + ReLU ----------------
// 32-bit voffset addressing: one uniform 64-bit base (hp), per-edge offset
// (se<<8)+voff stays in a VGPR -> global_load v, v_off, s[base] form.
__global__ void k_gather(const int* __restrict__ csr_src,
                         const int* __restrict__ rowbeg, const int* __restrict__ rowend,
                         const __hip_bfloat16* __restrict__ hB,
                         const float* __restrict__ asrc, const float* __restrict__ adst,
                         const float* __restrict__ bias, const float* __restrict__ gamma,
                         const float* __restrict__ beta, float* __restrict__ out, int N)
{
    int wave = threadIdx.x >> 6;
    int l = threadIdx.x & 63;
    int d = blockIdx.x * 4 + wave;
    if (d >= N) return;
    int head = l >> 4;
    const char* hp = (const char*)hB;
    unsigned voff = (unsigned)(l << 2);
    float ad = adst[d * NHEAD + head];
    int beg = __builtin_amdgcn_readfirstlane(rowbeg[d]);
    int end = __builtin_amdgcn_readfirstlane(rowend[d]);

    float ax0 = 0.f, ay0 = 0.f, dn0 = 0.f;
    float ax1 = 0.f, ay1 = 0.f, dn1 = 0.f;

    int idx = beg + (l & 15);
    int cl = idx < end ? idx : end - 1;
    int smine = csr_src[cl];
    float v = (idx < end) ? asrc[(unsigned)smine * NHEAD + head] : -1e30f;

    for (int c = beg; c < end; c += 16) {
        float ee = __expf(leaky(v + ad));        // padding -> exp(-2e29) = 0
        int scur = smine;
        int c2 = c + 16;
        if (c2 < end) {
            int idx2 = c2 + (l & 15);
            int cl2 = idx2 < end ? idx2 : end - 1;
            smine = csr_src[cl2];
            v = (idx2 < end) ? asrc[(unsigned)smine * NHEAD + head] : -1e30f;
        }

#define GLOAD(E_)                                                                     \
        unsigned se##E_ = (unsigned)__builtin_amdgcn_readlane(scur, (E_));            \
        unsigned hv##E_ = *(const unsigned*)(hp + ((se##E_ << 8) + voff));
#define GCONS(E_, AX_, AY_, DN_) {                                                    \
        float eb = __int_as_float(__builtin_amdgcn_ds_swizzle(                        \
            __float_as_int(ee), 0x10 | ((E_) << 5)));                                 \
        AX_ = fmaf(eb, __uint_as_float(hv##E_ << 16), AX_);                           \
        AY_ = fmaf(eb, __uint_as_float(hv##E_ & 0xffff0000u), AY_);  DN_ += eb;       \
    }
        { GLOAD(0) GLOAD(1) GLOAD(2) GLOAD(3) GLOAD(4) GLOAD(5) GLOAD(6) GLOAD(7)
          GCONS(0, ax0, ay0, dn0) GCONS(1, ax1, ay1, dn1)
          GCONS(2, ax0, ay0, dn0) GCONS(3, ax1, ay1, dn1)
          GCONS(4, ax0, ay0, dn0) GCONS(5, ax1, ay1, dn1)
          GCONS(6, ax0, ay0, dn0) GCONS(7, ax1, ay1, dn1) }
        { GLOAD(8) GLOAD(9) GLOAD(10) GLOAD(11) GLOAD(12) GLOAD(13) GLOAD(14) GLOAD(15)
          GCONS(8, ax0, ay0, dn0)  GCONS(9, ax1, ay1, dn1)
          GCONS(10, ax0, ay0, dn0) GCONS(11, ax1, ay1, dn1)
          GCONS(12, ax0, ay0, dn0) GCONS(13, ax1, ay1, dn1)
          GCONS(14, ax0, ay0, dn0) GCONS(15, ax1, ay1, dn1) }
#undef GLOAD
#undef GCONS
    }

    float accx = ax0 + ax1, accy = ay0 + ay1, den = dn0 + dn1;
    float inv = 1.f / (den + SM_EPS);
    float vx = accx * inv + bias[2 * l];
    float vy = accy * inv + bias[2 * l + 1];

    float s1 = vx + vy;
    float s2 = vx * vx + vy * vy;
    #pragma unroll
    for (int m = 32; m >= 1; m >>= 1) {
        s1 += __shfl_xor(s1, m, 64);
        s2 += __shfl_xor(s2, m, 64);
    }
    float mean = s1 * (1.f / OUT_DIM);
    float var = s2 * (1.f / OUT_DIM) - mean * mean;
    float r = rsqrtf(var + LN_EPS);
    float ox = (vx - mean) * r * gamma[2 * l] + beta[2 * l];
    float oy = (vy - mean) * r * gamma[2 * l + 1] + beta[2 * l + 1];
    ox = ox > 0.f ? ox : 0.f;
    oy = oy > 0.f ? oy : 0.f;
    *reinterpret_cast<float2*>(&out[(size_t)d * OUT_DIM + 2 * l]) = make_float2(ox, oy);
}

extern "C" void kernel_launch(void* const* d_in, const int* in_sizes, int n_in,
                              void* d_out, int out_size, void* d_ws, size_t ws_size,
                              hipStream_t stream) {
    const float* x      = (const float*)d_in[0];
    const int*   ei     = (const int*)d_in[1];
    const float* W      = (const float*)d_in[2];
    const float* a_src  = (const float*)d_in[3];
    const float* a_dst  = (const float*)d_in[4];
    const float* bias   = (const float*)d_in[5];
    const float* gamma  = (const float*)d_in[6];
    const float* beta   = (const float*)d_in[7];
    float* out = (float*)d_out;

    const int N = in_sizes[0] / IN_DIM;
    const int E = in_sizes[1] / 2;
    const int TOT = E + N;
    const int nbuck = (N + BDST - 1) >> NB_SHIFT;
    const int nblk_gemm = (N + 63) / 64;
    const int nblk_bin = (TOT + BIN_CHUNK - 1) / BIN_CHUNK;

    // workspace layout
    char* p = (char*)d_ws;
    __hip_bfloat16* hB = (__hip_bfloat16*)p;  p += (size_t)N * OUT_DIM * sizeof(__hip_bfloat16);
    __hip_bfloat16* WtB = (__hip_bfloat16*)p; p += (size_t)IN_DIM * OUT_DIM * sizeof(__hip_bfloat16);
    float* asrc   = (float*)p;                p += (size_t)N * NHEAD * sizeof(float);
    float* adst   = (float*)p;                p += (size_t)N * NHEAD * sizeof(float);
    int* bcur     = (int*)p;                  p += NBUCK_MAX * sizeof(int);
    int* rowbeg   = (int*)p;                  p += (size_t)N * sizeof(int);
    int* rowend   = (int*)p;                  p += (size_t)N * sizeof(int);
    unsigned* binned = (unsigned*)p;          p += (size_t)nbuck * BCAP * sizeof(unsigned);
    int* csr_src  = (int*)p;                  p += (size_t)nbuck * BCAP * sizeof(int);

    k_prepW<<<64, 256, 0, stream>>>(W, WtB, bcur);
    k_gemm_bin<<<nblk_bin + nblk_gemm, 256, 0, stream>>>(x, WtB, a_src, a_dst, hB, asrc, adst,
                                                         ei, bcur, binned, E, N, nblk_bin);
    k_bucket_csr<<<nbuck, 256, 0, stream>>>(binned, bcur, rowbeg, rowend, csr_src, N);
    k_gather<<<(N + 3) / 4, 256, 0, stream>>>(csr_src, rowbeg, rowend, hB, asrc, adst,
                                              bias, gamma, beta, out, N);
}